// Round 1
// baseline (700.193 us; speedup 1.0000x reference)
//
#include <hip/hip_runtime.h>

typedef __bf16 bf16;
typedef __bf16 bf16x4 __attribute__((ext_vector_type(4)));
typedef __bf16 bf16x8 __attribute__((ext_vector_type(8)));
typedef float  f32x4  __attribute__((ext_vector_type(4)));

// async global->LDS, 16B per lane; LDS dest is wave-uniform base + lane*16
__device__ inline void async_copy16(void* lds, const void* g) {
  __builtin_amdgcn_global_load_lds((const __attribute__((address_space(1))) void*)g,
                                   (__attribute__((address_space(3))) void*)lds,
                                   16, 0, 0);
}

// ---------------- fp32 -> bf16 convert (weights) ----------------
__global__ __launch_bounds__(256)
void f2bf_kernel(const float* __restrict__ in, bf16* __restrict__ out, int n4) {
  int i = blockIdx.x * 256 + threadIdx.x;
  if (i < n4) {
    float4 v = ((const float4*)in)[i];
    bf16x4 o;
    o[0] = (bf16)v.x; o[1] = (bf16)v.y; o[2] = (bf16)v.z; o[3] = (bf16)v.w;
    ((bf16x4*)out)[i] = o;
  }
}

// ---------------- x [B,C,HW] fp32 -> xb [B,HW,C] bf16 ----------------
__global__ __launch_bounds__(256)
void transpose_convert(const float* __restrict__ x, bf16* __restrict__ xb) {
  __shared__ float tile[64][65];
  const int tx = threadIdx.x & 15;
  const int ty = threadIdx.x >> 4;
  const int b   = blockIdx.z;
  const int c0  = blockIdx.y * 64;
  const int hw0 = blockIdx.x * 64;
  const float* xp = x + ((size_t)b * 2048 + c0) * 1024 + hw0;
#pragma unroll
  for (int i = 0; i < 4; ++i) {
    const int c = i * 16 + ty;
    const float4 v = *(const float4*)(xp + (size_t)c * 1024 + tx * 4);
    tile[c][tx * 4 + 0] = v.x; tile[c][tx * 4 + 1] = v.y;
    tile[c][tx * 4 + 2] = v.z; tile[c][tx * 4 + 3] = v.w;
  }
  __syncthreads();
  bf16* op = xb + ((size_t)b * 1024 + hw0) * 2048 + c0;
#pragma unroll
  for (int i = 0; i < 4; ++i) {
    const int hw = i * 16 + ty;
    bf16x4 o;
    o[0] = (bf16)tile[tx * 4 + 0][hw];
    o[1] = (bf16)tile[tx * 4 + 1][hw];
    o[2] = (bf16)tile[tx * 4 + 2][hw];
    o[3] = (bf16)tile[tx * 4 + 3][hw];
    *(bf16x4*)(op + (size_t)hw * 2048 + tx * 4) = o;
  }
}

// ---------------- m97-style bf16 GEMM: C[M,N] = A[M,K] * Bt[N,K]^T ----------------
// 128x128 block tile, BK=64, 4 waves (2x2), each wave 64x64 via 4x4 16x16x32 MFMAs.
template <bool F32OUT>
__global__ __launch_bounds__(256, 2)
void gemm_bt(const bf16* __restrict__ A, const bf16* __restrict__ Bt,
             bf16* __restrict__ Cb, float* __restrict__ Cf,
             const int K, const int N) {
  __shared__ bf16 As[128 * 64];
  __shared__ bf16 Bs[128 * 64];
  const int tid  = threadIdx.x;
  const int wave = tid >> 6;
  const int lane = tid & 63;
  const int bm = blockIdx.x, bn = blockIdx.y;
  const int wr = wave >> 1, wc = wave & 1;
  const int srow = lane >> 3;   // 8 rows per wave-chunk
  const int scol = lane & 7;    // 16B column chunk

  f32x4 acc[4][4];
#pragma unroll
  for (int r = 0; r < 4; ++r)
#pragma unroll
    for (int c = 0; c < 4; ++c) acc[r][c] = (f32x4){0.f, 0.f, 0.f, 0.f};

  const bf16* Ag = A + (size_t)(bm * 128) * K;
  const bf16* Bg = Bt + (size_t)(bn * 128) * K;

  const int mrow = lane & 15;
  const int kq = (lane >> 4) * 8;
  const bf16* Asw = As + (wr * 64) * 64;
  const bf16* Bsw = Bs + (wc * 64) * 64;

  for (int k0 = 0; k0 < K; k0 += 64) {
#pragma unroll
    for (int j = 0; j < 4; ++j) {
      const int row = j * 32 + wave * 8;  // wave-uniform LDS base row
      async_copy16((void*)(As + row * 64),
                   (const void*)(Ag + (size_t)(row + srow) * K + k0 + scol * 8));
      async_copy16((void*)(Bs + row * 64),
                   (const void*)(Bg + (size_t)(row + srow) * K + k0 + scol * 8));
    }
    __syncthreads();
#pragma unroll
    for (int kk = 0; kk < 2; ++kk) {
      bf16x8 af[4], bfr[4];
#pragma unroll
      for (int r = 0; r < 4; ++r)
        af[r] = *(const bf16x8*)(Asw + (r * 16 + mrow) * 64 + kk * 32 + kq);
#pragma unroll
      for (int c = 0; c < 4; ++c)
        bfr[c] = *(const bf16x8*)(Bsw + (c * 16 + mrow) * 64 + kk * 32 + kq);
#pragma unroll
      for (int r = 0; r < 4; ++r)
#pragma unroll
        for (int c = 0; c < 4; ++c)
          acc[r][c] = __builtin_amdgcn_mfma_f32_16x16x32_bf16(af[r], bfr[c], acc[r][c], 0, 0, 0);
    }
    __syncthreads();
  }

  // C/D layout: col = lane&15, row = (lane>>4)*4 + reg   [m89/m91-verified]
  const int crow = (lane >> 4) * 4;
  const int ccol = lane & 15;
#pragma unroll
  for (int r = 0; r < 4; ++r)
#pragma unroll
    for (int c = 0; c < 4; ++c)
#pragma unroll
      for (int i = 0; i < 4; ++i) {
        const int gm = bm * 128 + wr * 64 + r * 16 + crow + i;
        const int gn = bn * 128 + wc * 64 + c * 16 + ccol;
        if (F32OUT) Cf[(size_t)gm * N + gn] = acc[r][c][i];
        else        Cb[(size_t)gm * N + gn] = (bf16)acc[r][c][i];
      }
}

// ---------------- BN batch stats: per-channel sum / sumsq over 32768 rows ----------------
__global__ __launch_bounds__(256)
void bn_stats(const bf16* __restrict__ hb, float* __restrict__ S1, float* __restrict__ S2) {
  const int c0 = threadIdx.x * 4;
  const int r0 = blockIdx.x * 128;
  float s1[4] = {0, 0, 0, 0}, s2[4] = {0, 0, 0, 0};
  for (int i = 0; i < 128; ++i) {
    const bf16x4 v = *(const bf16x4*)(hb + (size_t)(r0 + i) * 1024 + c0);
#pragma unroll
    for (int j = 0; j < 4; ++j) {
      float xv = (float)v[j];
      s1[j] += xv;
      s2[j] += xv * xv;
    }
  }
#pragma unroll
  for (int j = 0; j < 4; ++j) {
    atomicAdd(&S1[c0 + j], s1[j]);
    atomicAdd(&S2[c0 + j], s2[j]);
  }
}

__global__ void bn_finalize(const float* __restrict__ S1, const float* __restrict__ S2,
                            const float* __restrict__ gamma, const float* __restrict__ beta,
                            float* __restrict__ scale, float* __restrict__ shift) {
  const int d = blockIdx.x * 256 + threadIdx.x;  // 1024 channels
  const float inv_n = 1.0f / 32768.0f;
  const float mean = S1[d] * inv_n;
  const float var  = S2[d] * inv_n - mean * mean;
  const float rstd = rsqrtf(var + 1e-5f);
  const float sc = gamma[d] * rstd;
  scale[d] = sc;
  shift[d] = beta[d] - mean * sc;
}

// ---------------- BN apply + ReLU, bf16 elementwise ----------------
__global__ __launch_bounds__(256)
void bn_relu(const bf16* __restrict__ hb, const float* __restrict__ scale,
             const float* __restrict__ shift, bf16* __restrict__ hn) {
  const size_t i = ((size_t)blockIdx.x * 256 + threadIdx.x) * 4;
  const int k = (int)(i & 1023);
  const bf16x4 v = *(const bf16x4*)(hb + i);
  const float4 sc = *(const float4*)(scale + k);
  const float4 sh = *(const float4*)(shift + k);
  bf16x4 o;
  o[0] = (bf16)fmaxf(0.f, (float)v[0] * sc.x + sh.x);
  o[1] = (bf16)fmaxf(0.f, (float)v[1] * sc.y + sh.y);
  o[2] = (bf16)fmaxf(0.f, (float)v[2] * sc.z + sh.z);
  o[3] = (bf16)fmaxf(0.f, (float)v[3] * sc.w + sh.w);
  *(bf16x4*)(hn + i) = o;
}

// ---------------- per-position L2 norm of f rows + per-batch accumulation: g[b][256] ----------------
__global__ __launch_bounds__(256)
void rownorm_g(const float* __restrict__ f, float* __restrict__ g) {
  __shared__ float buf[4][256];
  const int wave = threadIdx.x >> 6, lane = threadIdx.x & 63;
  const int b = blockIdx.x >> 3;
  const int r0 = (blockIdx.x & 7) * 128;
  float a0 = 0, a1 = 0, a2 = 0, a3 = 0;
  for (int i = 0; i < 32; ++i) {
    const int m = b * 1024 + r0 + wave * 32 + i;
    const float4 v = *(const float4*)(f + (size_t)m * 256 + lane * 4);
    float ss = v.x * v.x + v.y * v.y + v.z * v.z + v.w * v.w;
#pragma unroll
    for (int msk = 1; msk < 64; msk <<= 1) ss += __shfl_xor(ss, msk, 64);
    const float inv = 1.0f / fmaxf(sqrtf(ss), 1e-12f);
    a0 += v.x * inv; a1 += v.y * inv; a2 += v.z * inv; a3 += v.w * inv;
  }
  buf[wave][lane * 4 + 0] = a0;
  buf[wave][lane * 4 + 1] = a1;
  buf[wave][lane * 4 + 2] = a2;
  buf[wave][lane * 4 + 3] = a3;
  __syncthreads();
  const int col = threadIdx.x;
  const float s = buf[0][col] + buf[1][col] + buf[2][col] + buf[3][col];
  atomicAdd(&g[b * 256 + col], s);
}

// ---------------- normalize prototypes + sim = g . p_norm^T ----------------
__global__ __launch_bounds__(256)
void sim_kernel(const float* __restrict__ g, const float* __restrict__ protos,
                float* __restrict__ out) {
  const int wave = threadIdx.x >> 6, lane = threadIdx.x & 63;
  const int n = blockIdx.x * 4 + wave;  // 1000 prototypes, grid 250
  const float4 p = *(const float4*)(protos + (size_t)n * 256 + lane * 4);
  float ss = p.x * p.x + p.y * p.y + p.z * p.z + p.w * p.w;
#pragma unroll
  for (int msk = 1; msk < 64; msk <<= 1) ss += __shfl_xor(ss, msk, 64);
  const float inv = 1.0f / fmaxf(sqrtf(ss), 1e-12f);
  const float px = p.x * inv, py = p.y * inv, pz = p.z * inv, pw = p.w * inv;
  for (int b = 0; b < 32; ++b) {
    const float4 gv = *(const float4*)(g + b * 256 + lane * 4);
    float d = px * gv.x + py * gv.y + pz * gv.z + pw * gv.w;
#pragma unroll
    for (int msk = 1; msk < 64; msk <<= 1) d += __shfl_xor(d, msk, 64);
    if (lane == 0) out[b * 1000 + n] = d;
  }
}

extern "C" void kernel_launch(void* const* d_in, const int* in_sizes, int n_in,
                              void* d_out, int out_size, void* d_ws, size_t ws_size,
                              hipStream_t stream) {
  const float* x      = (const float*)d_in[0];  // [32,2048,32,32]
  const float* w1     = (const float*)d_in[1];  // [1024,2048]
  const float* gamma  = (const float*)d_in[2];  // [1024]
  const float* beta   = (const float*)d_in[3];  // [1024]
  const float* w2     = (const float*)d_in[4];  // [256,1024]
  const float* protos = (const float*)d_in[5];  // [1000,256]
  float* out = (float*)d_out;                   // [32,1000]

  char* ws = (char*)d_ws;
  // layout (bytes):
  //   0         : xb  [32768,2048] bf16  (128 MiB)  -- dead after gemm1
  //   0         : hn  [32768,1024] bf16  ( 64 MiB)  -- aliases xb
  //   64  MiB   : f   [32768, 256] fp32  ( 32 MiB)  -- aliases xb upper half
  //   128 MiB   : hb  [32768,1024] bf16  ( 64 MiB)
  //   192 MiB   : w1b (4 MiB), w2b (0.5 MiB), S1/S2/scale/shift (4 KiB each), g (32 KiB)
  bf16*  xb    = (bf16*)(ws);
  bf16*  hn    = (bf16*)(ws);
  float* f     = (float*)(ws + (size_t)67108864);
  bf16*  hb    = (bf16*)(ws + (size_t)134217728);
  bf16*  w1b   = (bf16*)(ws + (size_t)201326592);
  bf16*  w2b   = (bf16*)(ws + (size_t)205520896);
  float* S1    = (float*)(ws + (size_t)206045184);
  float* S2    = (float*)(ws + (size_t)206049280);
  float* scale = (float*)(ws + (size_t)206053376);
  float* shift = (float*)(ws + (size_t)206057472);
  float* g     = (float*)(ws + (size_t)206061568);

  hipMemsetAsync(S1, 0, 8192, stream);   // S1 + S2 contiguous
  hipMemsetAsync(g, 0, 32768, stream);

  f2bf_kernel<<<2048, 256, 0, stream>>>(w1, w1b, 524288);
  f2bf_kernel<<<256, 256, 0, stream>>>(w2, w2b, 65536);
  transpose_convert<<<dim3(16, 32, 32), 256, 0, stream>>>(x, xb);
  // h = x . w1^T   [32768,1024] bf16
  gemm_bt<false><<<dim3(256, 8), 256, 0, stream>>>(xb, w1b, hb, nullptr, 2048, 1024);
  bn_stats<<<256, 256, 0, stream>>>(hb, S1, S2);
  bn_finalize<<<4, 256, 0, stream>>>(S1, S2, gamma, beta, scale, shift);
  bn_relu<<<32768, 256, 0, stream>>>(hb, scale, shift, hn);
  // f = hn . w2^T  [32768,256] fp32
  gemm_bt<true><<<dim3(256, 2), 256, 0, stream>>>(hn, w2b, nullptr, f, 1024, 256);
  rownorm_g<<<256, 256, 0, stream>>>(f, g);
  sim_kernel<<<250, 256, 0, stream>>>(g, protos, out);
}

// Round 2
// 662.469 us; speedup vs baseline: 1.0569x; 1.0569x over previous
//
#include <hip/hip_runtime.h>

typedef __bf16 bf16;
typedef __bf16 bf16x4 __attribute__((ext_vector_type(4)));
typedef __bf16 bf16x8 __attribute__((ext_vector_type(8)));
typedef float  f32x4  __attribute__((ext_vector_type(4)));

// async global->LDS, 16B per lane; LDS dest is wave-uniform base + lane*16
__device__ inline void async_copy16(void* lds, const void* g) {
  __builtin_amdgcn_global_load_lds((const __attribute__((address_space(1))) void*)g,
                                   (__attribute__((address_space(3))) void*)lds,
                                   16, 0, 0);
}

// ---------------- fp32 -> bf16 convert (weights) ----------------
__global__ __launch_bounds__(256)
void f2bf_kernel(const float* __restrict__ in, bf16* __restrict__ out, int n4) {
  int i = blockIdx.x * 256 + threadIdx.x;
  if (i < n4) {
    float4 v = ((const float4*)in)[i];
    bf16x4 o;
    o[0] = (bf16)v.x; o[1] = (bf16)v.y; o[2] = (bf16)v.z; o[3] = (bf16)v.w;
    ((bf16x4*)out)[i] = o;
  }
}

// ---------------- x [B,C,HW] fp32 -> xb [B,HW,C] bf16 ----------------
__global__ __launch_bounds__(256)
void transpose_convert(const float* __restrict__ x, bf16* __restrict__ xb) {
  __shared__ float tile[64][65];
  const int tx = threadIdx.x & 15;
  const int ty = threadIdx.x >> 4;
  const int b   = blockIdx.z;
  const int c0  = blockIdx.y * 64;
  const int hw0 = blockIdx.x * 64;
  const float* xp = x + ((size_t)b * 2048 + c0) * 1024 + hw0;
#pragma unroll
  for (int i = 0; i < 4; ++i) {
    const int c = i * 16 + ty;
    const float4 v = *(const float4*)(xp + (size_t)c * 1024 + tx * 4);
    tile[c][tx * 4 + 0] = v.x; tile[c][tx * 4 + 1] = v.y;
    tile[c][tx * 4 + 2] = v.z; tile[c][tx * 4 + 3] = v.w;
  }
  __syncthreads();
  bf16* op = xb + ((size_t)b * 1024 + hw0) * 2048 + c0;
#pragma unroll
  for (int i = 0; i < 4; ++i) {
    const int hw = i * 16 + ty;
    bf16x4 o;
    o[0] = (bf16)tile[tx * 4 + 0][hw];
    o[1] = (bf16)tile[tx * 4 + 1][hw];
    o[2] = (bf16)tile[tx * 4 + 2][hw];
    o[3] = (bf16)tile[tx * 4 + 3][hw];
    *(bf16x4*)(op + (size_t)hw * 2048 + tx * 4) = o;
  }
}

// ---------------- m97-style bf16 GEMM: C[M,N] = A[M,K] * Bt[N,K]^T ----------------
// 128x128 block tile, BK=64, 4 waves (2x2), each wave 64x64 via 4x4 16x16x32 MFMAs.
// LDS chunk XOR-swizzle: logical 16B-chunk c of row r lives at physical chunk c^(r&7).
// Staging permutes source chunks so global_load_lds (lane*16 dest) lands swizzled;
// fragment reads apply the same XOR -> worst 2-way LDS aliasing (free on gfx950).
template <bool F32OUT>
__global__ __launch_bounds__(256, 4)
void gemm_bt(const bf16* __restrict__ A, const bf16* __restrict__ Bt,
             bf16* __restrict__ Cb, float* __restrict__ Cf,
             const int K, const int N) {
  __shared__ bf16 As[128 * 64];
  __shared__ bf16 Bs[128 * 64];
  const int tid  = threadIdx.x;
  const int wave = tid >> 6;
  const int lane = tid & 63;
  const int bm = blockIdx.y, bn = blockIdx.x;  // bn fastest: blocks sharing A run together
  const int wr = wave >> 1, wc = wave & 1;
  const int srow = lane >> 3;               // 8 rows per wave-chunk
  const int scol = (lane & 7) ^ srow;       // swizzled source chunk for this lane

  f32x4 acc[4][4];
#pragma unroll
  for (int r = 0; r < 4; ++r)
#pragma unroll
    for (int c = 0; c < 4; ++c) acc[r][c] = (f32x4){0.f, 0.f, 0.f, 0.f};

  const bf16* Ag = A + (size_t)(bm * 128) * K;
  const bf16* Bg = Bt + (size_t)(bn * 128) * K;

  const int mrow = lane & 15;
  const int kq = lane >> 4;                 // logical chunk quarter (0..3)
  const int sw = mrow & 7;                  // read-side XOR
  const bf16* Asw = As + (wr * 64) * 64;
  const bf16* Bsw = Bs + (wc * 64) * 64;

  for (int k0 = 0; k0 < K; k0 += 64) {
#pragma unroll
    for (int j = 0; j < 4; ++j) {
      const int row = j * 32 + wave * 8;    // wave-uniform LDS base row
      async_copy16((void*)(As + row * 64),
                   (const void*)(Ag + (size_t)(row + srow) * K + k0 + scol * 8));
      async_copy16((void*)(Bs + row * 64),
                   (const void*)(Bg + (size_t)(row + srow) * K + k0 + scol * 8));
    }
    __syncthreads();
#pragma unroll
    for (int kk = 0; kk < 2; ++kk) {
      bf16x8 af[4], bfr[4];
      const int lc = kk * 4 + kq;           // logical chunk 0..7
#pragma unroll
      for (int r = 0; r < 4; ++r)
        af[r] = *(const bf16x8*)(Asw + (r * 16 + mrow) * 64 + ((lc ^ sw) * 8));
#pragma unroll
      for (int c = 0; c < 4; ++c)
        bfr[c] = *(const bf16x8*)(Bsw + (c * 16 + mrow) * 64 + ((lc ^ sw) * 8));
#pragma unroll
      for (int r = 0; r < 4; ++r)
#pragma unroll
        for (int c = 0; c < 4; ++c)
          acc[r][c] = __builtin_amdgcn_mfma_f32_16x16x32_bf16(af[r], bfr[c], acc[r][c], 0, 0, 0);
    }
    __syncthreads();
  }

  // C/D layout: col = lane&15, row = (lane>>4)*4 + reg   [m89/m91-verified]
  const int crow = (lane >> 4) * 4;
  const int ccol = lane & 15;
#pragma unroll
  for (int r = 0; r < 4; ++r)
#pragma unroll
    for (int c = 0; c < 4; ++c)
#pragma unroll
      for (int i = 0; i < 4; ++i) {
        const int gm = bm * 128 + wr * 64 + r * 16 + crow + i;
        const int gn = bn * 128 + wc * 64 + c * 16 + ccol;
        if (F32OUT) Cf[(size_t)gm * N + gn] = acc[r][c][i];
        else        Cb[(size_t)gm * N + gn] = (bf16)acc[r][c][i];
      }
}

// ---------------- BN batch stats stage 1: per-block partial sum/sumsq ----------------
// P[b][0..1023] = sum over 128 rows, P[b][1024..2047] = sumsq. No atomics.
__global__ __launch_bounds__(256)
void bn_stats(const bf16* __restrict__ hb, float* __restrict__ P) {
  __shared__ float ls1[2][128][9];
  __shared__ float ls2[2][128][9];
  const int t = threadIdx.x;
  const int c = t & 127, rg = t >> 7;
  const bf16* hp = hb + (size_t)blockIdx.x * 128 * 1024 + c * 8;
  float s1[8], s2[8];
#pragma unroll
  for (int j = 0; j < 8; ++j) { s1[j] = 0.f; s2[j] = 0.f; }
  for (int i = 0; i < 64; ++i) {
    const bf16x8 v = *(const bf16x8*)(hp + (size_t)(i * 2 + rg) * 1024);
#pragma unroll
    for (int j = 0; j < 8; ++j) {
      const float xv = (float)v[j];
      s1[j] += xv; s2[j] += xv * xv;
    }
  }
#pragma unroll
  for (int j = 0; j < 8; ++j) { ls1[rg][c][j] = s1[j]; ls2[rg][c][j] = s2[j]; }
  __syncthreads();
  float* Pb = P + (size_t)blockIdx.x * 2048;
  if (rg == 0) {
#pragma unroll
    for (int j = 0; j < 8; ++j) Pb[c * 8 + j] = ls1[0][c][j] + ls1[1][c][j];
  } else {
#pragma unroll
    for (int j = 0; j < 8; ++j) Pb[1024 + c * 8 + j] = ls2[0][c][j] + ls2[1][c][j];
  }
}

// ---------------- BN stats stage 2: reduce partials -> scale/shift ----------------
__global__ __launch_bounds__(256)
void bn_finalize(const float* __restrict__ P,
                 const float* __restrict__ gamma, const float* __restrict__ beta,
                 float* __restrict__ scale, float* __restrict__ shift) {
  const int d = blockIdx.x * 256 + threadIdx.x;  // 1024 channels
  float s1 = 0.f, s2 = 0.f;
  for (int p = 0; p < 256; ++p) {
    s1 += P[(size_t)p * 2048 + d];
    s2 += P[(size_t)p * 2048 + 1024 + d];
  }
  const float inv_n = 1.0f / 32768.0f;
  const float mean = s1 * inv_n;
  const float var  = s2 * inv_n - mean * mean;
  const float rstd = rsqrtf(var + 1e-5f);
  const float sc = gamma[d] * rstd;
  scale[d] = sc;
  shift[d] = beta[d] - mean * sc;
}

// ---------------- BN apply + ReLU, bf16 elementwise (16B/lane) ----------------
__global__ __launch_bounds__(256)
void bn_relu(const bf16* __restrict__ hb, const float* __restrict__ scale,
             const float* __restrict__ shift, bf16* __restrict__ hn) {
  const size_t i = ((size_t)blockIdx.x * 256 + threadIdx.x) * 8;
  const int k = (int)(i & 1023);
  const bf16x8 v = *(const bf16x8*)(hb + i);
  bf16x8 o;
#pragma unroll
  for (int j = 0; j < 8; j += 4) {
    const float4 sc = *(const float4*)(scale + k + j);
    const float4 sh = *(const float4*)(shift + k + j);
    o[j + 0] = (bf16)fmaxf(0.f, (float)v[j + 0] * sc.x + sh.x);
    o[j + 1] = (bf16)fmaxf(0.f, (float)v[j + 1] * sc.y + sh.y);
    o[j + 2] = (bf16)fmaxf(0.f, (float)v[j + 2] * sc.z + sh.z);
    o[j + 3] = (bf16)fmaxf(0.f, (float)v[j + 3] * sc.w + sh.w);
  }
  *(bf16x8*)(hn + i) = o;
}

// ---------------- per-position L2 norm of f rows + per-batch accumulation: g[b][256] ----------------
__global__ __launch_bounds__(256)
void rownorm_g(const float* __restrict__ f, float* __restrict__ g) {
  __shared__ float buf[4][256];
  const int wave = threadIdx.x >> 6, lane = threadIdx.x & 63;
  const int b = blockIdx.x >> 3;
  const int r0 = (blockIdx.x & 7) * 128;
  float a0 = 0, a1 = 0, a2 = 0, a3 = 0;
  for (int i = 0; i < 32; ++i) {
    const int m = b * 1024 + r0 + wave * 32 + i;
    const float4 v = *(const float4*)(f + (size_t)m * 256 + lane * 4);
    float ss = v.x * v.x + v.y * v.y + v.z * v.z + v.w * v.w;
#pragma unroll
    for (int msk = 1; msk < 64; msk <<= 1) ss += __shfl_xor(ss, msk, 64);
    const float inv = 1.0f / fmaxf(sqrtf(ss), 1e-12f);
    a0 += v.x * inv; a1 += v.y * inv; a2 += v.z * inv; a3 += v.w * inv;
  }
  buf[wave][lane * 4 + 0] = a0;
  buf[wave][lane * 4 + 1] = a1;
  buf[wave][lane * 4 + 2] = a2;
  buf[wave][lane * 4 + 3] = a3;
  __syncthreads();
  const int col = threadIdx.x;
  const float s = buf[0][col] + buf[1][col] + buf[2][col] + buf[3][col];
  atomicAdd(&g[b * 256 + col], s);
}

// ---------------- normalize prototypes + sim = g . p_norm^T ----------------
__global__ __launch_bounds__(256)
void sim_kernel(const float* __restrict__ g, const float* __restrict__ protos,
                float* __restrict__ out) {
  const int wave = threadIdx.x >> 6, lane = threadIdx.x & 63;
  const int n = blockIdx.x * 4 + wave;  // 1000 prototypes, grid 250
  const float4 p = *(const float4*)(protos + (size_t)n * 256 + lane * 4);
  float ss = p.x * p.x + p.y * p.y + p.z * p.z + p.w * p.w;
#pragma unroll
  for (int msk = 1; msk < 64; msk <<= 1) ss += __shfl_xor(ss, msk, 64);
  const float inv = 1.0f / fmaxf(sqrtf(ss), 1e-12f);
  const float px = p.x * inv, py = p.y * inv, pz = p.z * inv, pw = p.w * inv;
  for (int b = 0; b < 32; ++b) {
    const float4 gv = *(const float4*)(g + b * 256 + lane * 4);
    float d = px * gv.x + py * gv.y + pz * gv.z + pw * gv.w;
#pragma unroll
    for (int msk = 1; msk < 64; msk <<= 1) d += __shfl_xor(d, msk, 64);
    if (lane == 0) out[b * 1000 + n] = d;
  }
}

extern "C" void kernel_launch(void* const* d_in, const int* in_sizes, int n_in,
                              void* d_out, int out_size, void* d_ws, size_t ws_size,
                              hipStream_t stream) {
  const float* x      = (const float*)d_in[0];  // [32,2048,32,32]
  const float* w1     = (const float*)d_in[1];  // [1024,2048]
  const float* gamma  = (const float*)d_in[2];  // [1024]
  const float* beta   = (const float*)d_in[3];  // [1024]
  const float* w2     = (const float*)d_in[4];  // [256,1024]
  const float* protos = (const float*)d_in[5];  // [1000,256]
  float* out = (float*)d_out;                   // [32,1000]

  char* ws = (char*)d_ws;
  // layout (bytes):
  //   0         : xb  [32768,2048] bf16  (128 MiB)  -- dead after gemm1
  //   0         : hn  [32768,1024] bf16  ( 64 MiB)  -- aliases xb
  //   64  MiB   : f   [32768, 256] fp32  ( 32 MiB)  -- aliases xb upper half
  //   96  MiB   : P   [256][2048]  fp32  (  2 MiB)  -- aliases xb upper half
  //   128 MiB   : hb  [32768,1024] bf16  ( 64 MiB)
  //   192 MiB   : w1b (4 MiB), w2b (0.5 MiB), scale/shift (4 KiB each), g (32 KiB)
  bf16*  xb    = (bf16*)(ws);
  bf16*  hn    = (bf16*)(ws);
  float* f     = (float*)(ws + (size_t)67108864);
  float* P     = (float*)(ws + (size_t)100663296);
  bf16*  hb    = (bf16*)(ws + (size_t)134217728);
  bf16*  w1b   = (bf16*)(ws + (size_t)201326592);
  bf16*  w2b   = (bf16*)(ws + (size_t)205520896);
  float* scale = (float*)(ws + (size_t)206045184);
  float* shift = (float*)(ws + (size_t)206049280);
  float* g     = (float*)(ws + (size_t)206053376);

  hipMemsetAsync(g, 0, 32768, stream);

  f2bf_kernel<<<2048, 256, 0, stream>>>(w1, w1b, 524288);
  f2bf_kernel<<<256, 256, 0, stream>>>(w2, w2b, 65536);
  transpose_convert<<<dim3(16, 32, 32), 256, 0, stream>>>(x, xb);
  // h = x . w1^T   [32768,1024] bf16
  gemm_bt<false><<<dim3(8, 256), 256, 0, stream>>>(xb, w1b, hb, nullptr, 2048, 1024);
  bn_stats<<<256, 256, 0, stream>>>(hb, P);
  bn_finalize<<<4, 256, 0, stream>>>(P, gamma, beta, scale, shift);
  bn_relu<<<16384, 256, 0, stream>>>(hb, scale, shift, hn);
  // f = hn . w2^T  [32768,256] fp32
  gemm_bt<true><<<dim3(2, 256), 256, 0, stream>>>(hn, w2b, nullptr, f, 1024, 256);
  rownorm_g<<<256, 256, 0, stream>>>(f, g);
  sim_kernel<<<250, 256, 0, stream>>>(g, protos, out);
}

// Round 3
// 612.163 us; speedup vs baseline: 1.1438x; 1.0822x over previous
//
#include <hip/hip_runtime.h>

typedef __bf16 bf16;
typedef __bf16 bf16x4 __attribute__((ext_vector_type(4)));
typedef __bf16 bf16x8 __attribute__((ext_vector_type(8)));
typedef float  f32x4  __attribute__((ext_vector_type(4)));

// async global->LDS, 16B per lane; LDS dest is wave-uniform base + lane*16
__device__ inline void async_copy16(void* lds, const void* g) {
  __builtin_amdgcn_global_load_lds((const __attribute__((address_space(1))) void*)g,
                                   (__attribute__((address_space(3))) void*)lds,
                                   16, 0, 0);
}

// ---------------- fp32 -> bf16 convert (weights) ----------------
__global__ __launch_bounds__(256)
void f2bf_kernel(const float* __restrict__ in, bf16* __restrict__ out, int n4) {
  int i = blockIdx.x * 256 + threadIdx.x;
  if (i < n4) {
    float4 v = ((const float4*)in)[i];
    bf16x4 o;
    o[0] = (bf16)v.x; o[1] = (bf16)v.y; o[2] = (bf16)v.z; o[3] = (bf16)v.w;
    ((bf16x4*)out)[i] = o;
  }
}

// ---------------- x [B,C,HW] fp32 -> xb [B,HW,C] bf16 ----------------
__global__ __launch_bounds__(256)
void transpose_convert(const float* __restrict__ x, bf16* __restrict__ xb) {
  __shared__ float tile[64][65];
  const int tx = threadIdx.x & 15;
  const int ty = threadIdx.x >> 4;
  const int b   = blockIdx.z;
  const int c0  = blockIdx.y * 64;
  const int hw0 = blockIdx.x * 64;
  const float* xp = x + ((size_t)b * 2048 + c0) * 1024 + hw0;
#pragma unroll
  for (int i = 0; i < 4; ++i) {
    const int c = i * 16 + ty;
    const float4 v = *(const float4*)(xp + (size_t)c * 1024 + tx * 4);
    tile[c][tx * 4 + 0] = v.x; tile[c][tx * 4 + 1] = v.y;
    tile[c][tx * 4 + 2] = v.z; tile[c][tx * 4 + 3] = v.w;
  }
  __syncthreads();
  bf16* op = xb + ((size_t)b * 1024 + hw0) * 2048 + c0;
#pragma unroll
  for (int i = 0; i < 4; ++i) {
    const int hw = i * 16 + ty;
    bf16x4 o;
    o[0] = (bf16)tile[tx * 4 + 0][hw];
    o[1] = (bf16)tile[tx * 4 + 1][hw];
    o[2] = (bf16)tile[tx * 4 + 2][hw];
    o[3] = (bf16)tile[tx * 4 + 3][hw];
    *(bf16x4*)(op + (size_t)hw * 2048 + tx * 4) = o;
  }
}

// ---------------- GEMM1: hb[M,1024] = xb[M,2048] . w1b^T, fused BN-stats partials ----------------
// 128x128 tile, BK=64, XOR-swizzled LDS (conflict-free), XCD-aware block mapping:
// xcd = id&7; within an XCD bn iterates fastest so the 8 blocks sharing an A-tile
// are temporally adjacent on the SAME XCD -> A fetched ~once from HBM.
__global__ __launch_bounds__(256, 4)
void gemm1(const bf16* __restrict__ A, const bf16* __restrict__ Bt,
           bf16* __restrict__ Cb, float* __restrict__ S1, float* __restrict__ S2) {
  __shared__ __align__(16) bf16 As[128 * 64];
  __shared__ __align__(16) bf16 Bs[128 * 64];
  const int K = 2048, N = 1024;
  const int tid  = threadIdx.x;
  const int wave = tid >> 6;
  const int lane = tid & 63;
  const int id = blockIdx.x;                 // 2048 blocks
  const int bm = (id & 7) * 32 + ((id >> 3) >> 3);
  const int bn = (id >> 3) & 7;
  const int wr = wave >> 1, wc = wave & 1;
  const int srow = lane >> 3;
  const int scol = (lane & 7) ^ srow;        // staged (swizzled) source chunk

  f32x4 acc[4][4];
#pragma unroll
  for (int r = 0; r < 4; ++r)
#pragma unroll
    for (int c = 0; c < 4; ++c) acc[r][c] = (f32x4){0.f, 0.f, 0.f, 0.f};

  const bf16* Ag = A + (size_t)(bm * 128) * K;
  const bf16* Bg = Bt + (size_t)(bn * 128) * K;

  const int mrow = lane & 15;
  const int kq = lane >> 4;
  const int sw = mrow & 7;
  const bf16* Asw = As + (wr * 64) * 64;
  const bf16* Bsw = Bs + (wc * 64) * 64;

  for (int k0 = 0; k0 < K; k0 += 64) {
#pragma unroll
    for (int j = 0; j < 4; ++j) {
      const int row = j * 32 + wave * 8;
      async_copy16((void*)(As + row * 64),
                   (const void*)(Ag + (size_t)(row + srow) * K + k0 + scol * 8));
      async_copy16((void*)(Bs + row * 64),
                   (const void*)(Bg + (size_t)(row + srow) * K + k0 + scol * 8));
    }
    __syncthreads();
#pragma unroll
    for (int kk = 0; kk < 2; ++kk) {
      bf16x8 af[4], bfr[4];
      const int lc = kk * 4 + kq;
#pragma unroll
      for (int r = 0; r < 4; ++r)
        af[r] = *(const bf16x8*)(Asw + (r * 16 + mrow) * 64 + ((lc ^ sw) * 8));
#pragma unroll
      for (int c = 0; c < 4; ++c)
        bfr[c] = *(const bf16x8*)(Bsw + (c * 16 + mrow) * 64 + ((lc ^ sw) * 8));
#pragma unroll
      for (int r = 0; r < 4; ++r)
#pragma unroll
        for (int c = 0; c < 4; ++c)
          acc[r][c] = __builtin_amdgcn_mfma_f32_16x16x32_bf16(af[r], bfr[c], acc[r][c], 0, 0, 0);
    }
    __syncthreads();
  }

  // C/D layout: col = lane&15, row = (lane>>4)*4 + reg
  const int crow = (lane >> 4) * 4;
  const int ccol = lane & 15;
#pragma unroll
  for (int r = 0; r < 4; ++r)
#pragma unroll
    for (int c = 0; c < 4; ++c)
#pragma unroll
      for (int i = 0; i < 4; ++i) {
        const int gm = bm * 128 + wr * 64 + r * 16 + crow + i;
        const int gn = bn * 128 + wc * 64 + c * 16 + ccol;
        Cb[(size_t)gm * N + gn] = (bf16)acc[r][c][i];
      }

  // Fused BN-stats partials: per-column sum/sumsq over this block's 128 rows.
  float s1[4], s2[4];
#pragma unroll
  for (int c = 0; c < 4; ++c) {
    float a = 0.f, b = 0.f;
#pragma unroll
    for (int r = 0; r < 4; ++r)
#pragma unroll
      for (int i = 0; i < 4; ++i) { const float v = acc[r][c][i]; a += v; b += v * v; }
    // reduce over row-quadrant lanes (same ccol, different lane>>4)
#pragma unroll
    for (int msk = 16; msk < 64; msk <<= 1) { a += __shfl_xor(a, msk, 64); b += __shfl_xor(b, msk, 64); }
    s1[c] = a; s2[c] = b;
  }
  float* S1s = (float*)As;        // [2][128]
  float* S2s = S1s + 256;         // [2][128]
  if ((lane & 15) == lane) {      // lanes 0..15 of each wave
#pragma unroll
    for (int c = 0; c < 4; ++c) {
      S1s[wr * 128 + wc * 64 + c * 16 + lane] = s1[c];
      S2s[wr * 128 + wc * 64 + c * 16 + lane] = s2[c];
    }
  }
  __syncthreads();
  if (tid < 128) {
    atomicAdd(&S1[bn * 128 + tid], S1s[tid] + S1s[128 + tid]);
    atomicAdd(&S2[bn * 128 + tid], S2s[tid] + S2s[128 + tid]);
  }
}

// ---------------- BN finalize: S1/S2 -> scale/shift ----------------
__global__ __launch_bounds__(256)
void bn_finalize(const float* __restrict__ S1, const float* __restrict__ S2,
                 const float* __restrict__ gamma, const float* __restrict__ beta,
                 float* __restrict__ scale, float* __restrict__ shift) {
  const int d = blockIdx.x * 256 + threadIdx.x;  // 1024 channels
  const float inv_n = 1.0f / 32768.0f;
  const float mean = S1[d] * inv_n;
  const float var  = S2[d] * inv_n - mean * mean;
  const float rstd = rsqrtf(var + 1e-5f);
  const float sc = gamma[d] * rstd;
  scale[d] = sc;
  shift[d] = beta[d] - mean * sc;
}

// ---------------- GEMM2 fused: f = relu(hb*scale+shift) . w2b^T, row-L2-normalize, g-accumulate --------
// 512 threads (8 waves, 2x4), tile 128m x 256n, BK=64. BN+ReLU applied on A-fragments.
// Epilogue: per-row ss (shfl+LDS), inv = 1/max(sqrt(ss),eps), g[b][n] += sum_m f*inv.
__global__ __launch_bounds__(512, 4)
void gemm2f(const bf16* __restrict__ A, const bf16* __restrict__ Bt,
            const float* __restrict__ scale, const float* __restrict__ shift,
            float* __restrict__ g) {
  __shared__ __align__(16) bf16 As[128 * 64];
  __shared__ __align__(16) bf16 Bs[256 * 64];
  const int K = 1024;
  const int tid  = threadIdx.x;
  const int wave = tid >> 6;
  const int lane = tid & 63;
  const int bm = blockIdx.x;                 // 256 blocks, full 256-wide rows
  const int wr = wave >> 2, wc = wave & 3;   // 2 x 4 wave grid, wave tile 64x64
  const int srow = lane >> 3;
  const int scol = (lane & 7) ^ srow;

  f32x4 acc[4][4];
#pragma unroll
  for (int r = 0; r < 4; ++r)
#pragma unroll
    for (int c = 0; c < 4; ++c) acc[r][c] = (f32x4){0.f, 0.f, 0.f, 0.f};

  const bf16* Ag = A + (size_t)(bm * 128) * K;

  const int mrow = lane & 15;
  const int kq = lane >> 4;
  const int sw = mrow & 7;
  const bf16* Asw = As + (wr * 64) * 64;
  const bf16* Bsw = Bs + (wc * 64) * 64;

  for (int k0 = 0; k0 < K; k0 += 64) {
    // stage A: 128 rows (2 async/wave), B: 256 rows (4 async/wave)
#pragma unroll
    for (int j = 0; j < 2; ++j) {
      const int row = wave * 16 + j * 8;
      async_copy16((void*)(As + row * 64),
                   (const void*)(Ag + (size_t)(row + srow) * K + k0 + scol * 8));
    }
#pragma unroll
    for (int j = 0; j < 4; ++j) {
      const int row = wave * 32 + j * 8;
      async_copy16((void*)(Bs + row * 64),
                   (const void*)(Bt + (size_t)(row + srow) * K + k0 + scol * 8));
    }
    __syncthreads();
#pragma unroll
    for (int kk = 0; kk < 2; ++kk) {
      const int lc = kk * 4 + kq;           // logical k-chunk; actual k = k0 + lc*8 + j
      const int kbase = k0 + lc * 8;
      const float4 sc0 = *(const float4*)(scale + kbase);
      const float4 sc1 = *(const float4*)(scale + kbase + 4);
      const float4 sh0 = *(const float4*)(shift + kbase);
      const float4 sh1 = *(const float4*)(shift + kbase + 4);
      const float scv[8] = {sc0.x, sc0.y, sc0.z, sc0.w, sc1.x, sc1.y, sc1.z, sc1.w};
      const float shv[8] = {sh0.x, sh0.y, sh0.z, sh0.w, sh1.x, sh1.y, sh1.z, sh1.w};
      bf16x8 af[4], bfr[4];
#pragma unroll
      for (int r = 0; r < 4; ++r) {
        bf16x8 a = *(const bf16x8*)(Asw + (r * 16 + mrow) * 64 + ((lc ^ sw) * 8));
#pragma unroll
        for (int j = 0; j < 8; ++j)
          a[j] = (bf16)fmaxf(0.f, fmaf((float)a[j], scv[j], shv[j]));
        af[r] = a;
      }
#pragma unroll
      for (int c = 0; c < 4; ++c)
        bfr[c] = *(const bf16x8*)(Bsw + (c * 16 + mrow) * 64 + ((lc ^ sw) * 8));
#pragma unroll
      for (int r = 0; r < 4; ++r)
#pragma unroll
        for (int c = 0; c < 4; ++c)
          acc[r][c] = __builtin_amdgcn_mfma_f32_16x16x32_bf16(af[r], bfr[c], acc[r][c], 0, 0, 0);
    }
    __syncthreads();
  }

  // ---- epilogue: row L2 norms + g accumulation (f never hits HBM) ----
  float* ss4   = (float*)As;      // [4 wc][128 rows]
  float* inv_s = ss4 + 512;       // [128]
  const int q = lane >> 4;
  // (a) per-row sum of squares over this wave's 64 cols
#pragma unroll
  for (int r = 0; r < 4; ++r) {
    float ssv[4];
#pragma unroll
    for (int i = 0; i < 4; ++i) {
      float s = 0.f;
#pragma unroll
      for (int c = 0; c < 4; ++c) { const float v = acc[r][c][i]; s += v * v; }
#pragma unroll
      for (int msk = 1; msk < 16; msk <<= 1) s += __shfl_xor(s, msk, 64);
      ssv[i] = s;
    }
    if ((lane & 15) == 0)
#pragma unroll
      for (int i = 0; i < 4; ++i)
        ss4[wc * 128 + wr * 64 + r * 16 + q * 4 + i] = ssv[i];
  }
  __syncthreads();
  if (tid < 128) {
    const float rs = ss4[tid] + ss4[128 + tid] + ss4[256 + tid] + ss4[384 + tid];
    inv_s[tid] = 1.0f / fmaxf(sqrtf(rs), 1e-12f);
  }
  __syncthreads();
  // (b) g[b][col] += sum over rows of f*inv
  const int b = bm >> 3;
  const int ccol = lane & 15;
#pragma unroll
  for (int c = 0; c < 4; ++c) {
    float gl = 0.f;
#pragma unroll
    for (int r = 0; r < 4; ++r)
#pragma unroll
      for (int i = 0; i < 4; ++i)
        gl += acc[r][c][i] * inv_s[wr * 64 + r * 16 + q * 4 + i];
#pragma unroll
    for (int msk = 16; msk < 64; msk <<= 1) gl += __shfl_xor(gl, msk, 64);
    if ((lane & 48) == 0)
      atomicAdd(&g[b * 256 + wc * 64 + c * 16 + ccol], gl);
  }
}

// ---------------- normalize prototypes + sim = g . p_norm^T ----------------
__global__ __launch_bounds__(256)
void sim_kernel(const float* __restrict__ g, const float* __restrict__ protos,
                float* __restrict__ out) {
  const int wave = threadIdx.x >> 6, lane = threadIdx.x & 63;
  const int n = blockIdx.x * 4 + wave;  // 1000 prototypes, grid 250
  const float4 p = *(const float4*)(protos + (size_t)n * 256 + lane * 4);
  float ss = p.x * p.x + p.y * p.y + p.z * p.z + p.w * p.w;
#pragma unroll
  for (int msk = 1; msk < 64; msk <<= 1) ss += __shfl_xor(ss, msk, 64);
  const float inv = 1.0f / fmaxf(sqrtf(ss), 1e-12f);
  const float px = p.x * inv, py = p.y * inv, pz = p.z * inv, pw = p.w * inv;
  for (int b = 0; b < 32; ++b) {
    const float4 gv = *(const float4*)(g + b * 256 + lane * 4);
    float d = px * gv.x + py * gv.y + pz * gv.z + pw * gv.w;
#pragma unroll
    for (int msk = 1; msk < 64; msk <<= 1) d += __shfl_xor(d, msk, 64);
    if (lane == 0) out[b * 1000 + n] = d;
  }
}

extern "C" void kernel_launch(void* const* d_in, const int* in_sizes, int n_in,
                              void* d_out, int out_size, void* d_ws, size_t ws_size,
                              hipStream_t stream) {
  const float* x      = (const float*)d_in[0];  // [32,2048,32,32]
  const float* w1     = (const float*)d_in[1];  // [1024,2048]
  const float* gamma  = (const float*)d_in[2];  // [1024]
  const float* beta   = (const float*)d_in[3];  // [1024]
  const float* w2     = (const float*)d_in[4];  // [256,1024]
  const float* protos = (const float*)d_in[5];  // [1000,256]
  float* out = (float*)d_out;                   // [32,1000]

  char* ws = (char*)d_ws;
  // layout (bytes):
  //   0         : xb  [32768,2048] bf16  (128 MiB)
  //   128 MiB   : hb  [32768,1024] bf16  ( 64 MiB)
  //   192 MiB   : w1b (4 MiB), w2b (0.5 MiB)
  //   then      : S1(4K) S2(4K) g(32K) scale(4K) shift(4K)
  bf16*  xb    = (bf16*)(ws);
  bf16*  hb    = (bf16*)(ws + (size_t)134217728);
  bf16*  w1b   = (bf16*)(ws + (size_t)201326592);
  bf16*  w2b   = (bf16*)(ws + (size_t)205520896);
  float* S1    = (float*)(ws + (size_t)206045184);
  float* S2    = (float*)(ws + (size_t)206049280);
  float* g     = (float*)(ws + (size_t)206053376);
  float* scale = (float*)(ws + (size_t)206086144);
  float* shift = (float*)(ws + (size_t)206090240);

  hipMemsetAsync(S1, 0, 40960, stream);  // S1 + S2 + g contiguous

  f2bf_kernel<<<2048, 256, 0, stream>>>(w1, w1b, 524288);
  f2bf_kernel<<<256, 256, 0, stream>>>(w2, w2b, 65536);
  transpose_convert<<<dim3(16, 32, 32), 256, 0, stream>>>(x, xb);
  gemm1<<<2048, 256, 0, stream>>>(xb, w1b, hb, S1, S2);
  bn_finalize<<<4, 256, 0, stream>>>(S1, S2, gamma, beta, scale, shift);
  gemm2f<<<256, 512, 0, stream>>>(hb, w2b, scale, shift, g);
  sim_kernel<<<250, 256, 0, stream>>>(g, protos, out);
}